// Round 1
// baseline (709.512 us; speedup 1.0000x reference)
//
#include <hip/hip_runtime.h>
#include <cstdint>
#include <cstddef>

#define B_SZ 16384
#define DIN  1024
#define DOUT 1024

typedef short bf16x8 __attribute__((ext_vector_type(8)));
typedef float f32x4  __attribute__((ext_vector_type(4)));

static __device__ __forceinline__ short f2bf(float f) {
    union { float f; unsigned u; } v; v.f = f;
    unsigned r = v.u + 0x7fffu + ((v.u >> 16) & 1u);
    return (short)(r >> 16);
}

// ---------------- conversion: fp32 -> bf16 (vectorized x4) ----------------
__global__ __launch_bounds__(256) void convert_f32_bf16(const float* __restrict__ in,
                                                        short* __restrict__ out, int n4) {
    int i = blockIdx.x * 256 + threadIdx.x;
    if (i < n4) {
        float4 v = ((const float4*)in)[i];
        short4 o;
        o.x = f2bf(v.x); o.y = f2bf(v.y); o.z = f2bf(v.z); o.w = f2bf(v.w);
        ((short4*)out)[i] = o;
    }
}

// ---------------- init: eff_lr reduction + zero colsumsq ----------------
__global__ __launch_bounds__(256) void init_kernel(const float* __restrict__ plast,
                                                   float* __restrict__ eff_lr,
                                                   float* __restrict__ colsumsq) {
    int tid = threadIdx.x;
    float s = 0.f;
    for (int i = tid; i < B_SZ; i += 256) s += plast[i];
    __shared__ float red[256];
    red[tid] = s; __syncthreads();
    for (int off = 128; off > 0; off >>= 1) {
        if (tid < off) red[tid] += red[tid + off];
        __syncthreads();
    }
    if (tid == 0) eff_lr[0] = (red[0] / (float)B_SZ) * 0.1f;
    for (int i = tid; i < DOUT; i += 256) colsumsq[i] = 0.f;
}

// ---------------- dual GEMM: slow = x@Ws^T, fast = x@Wf^T ----------------
// tile 128(M) x 64(N), BK=32, 4 waves as 2x2; wave tile 64x32 -> 4x2 mfma tiles
#define LSTR 40   // LDS row stride in bf16 elems (32 + 8 pad, keeps 16B align)

__global__ __launch_bounds__(256) void dual_gemm(
    const short* __restrict__ Xb, const short* __restrict__ Ws, const short* __restrict__ Wf,
    float* __restrict__ slow_out, float* __restrict__ fast_out)
{
    __shared__ short lA[128 * LSTR];
    __shared__ short lBs[64 * LSTR];
    __shared__ short lBf[64 * LSTR];
    const int tid = threadIdx.x;
    const int lane = tid & 63;
    const int wave = tid >> 6;
    const int wm = wave & 1, wn = wave >> 1;
    const int quad = lane >> 4, l16 = lane & 15;
    const int m0 = blockIdx.x * 128;
    const int n0 = blockIdx.y * 64;
    const int srow = tid >> 2;        // 0..63
    const int scol = (tid & 3) * 8;   // 0,8,16,24

    f32x4 accS[4][2] = {};
    f32x4 accF[4][2] = {};

    for (int k0 = 0; k0 < DIN; k0 += 32) {
        bf16x8 a0 = *(const bf16x8*)&Xb[(size_t)(m0 + srow) * DIN + k0 + scol];
        bf16x8 a1 = *(const bf16x8*)&Xb[(size_t)(m0 + srow + 64) * DIN + k0 + scol];
        bf16x8 b0 = *(const bf16x8*)&Ws[(size_t)(n0 + srow) * DIN + k0 + scol];
        bf16x8 b1 = *(const bf16x8*)&Wf[(size_t)(n0 + srow) * DIN + k0 + scol];
        *(bf16x8*)&lA[srow * LSTR + scol] = a0;
        *(bf16x8*)&lA[(srow + 64) * LSTR + scol] = a1;
        *(bf16x8*)&lBs[srow * LSTR + scol] = b0;
        *(bf16x8*)&lBf[srow * LSTR + scol] = b1;
        __syncthreads();
        bf16x8 af[4], bsf[2], bff[2];
        #pragma unroll
        for (int t = 0; t < 4; ++t)
            af[t] = *(const bf16x8*)&lA[(wm * 64 + t * 16 + l16) * LSTR + quad * 8];
        #pragma unroll
        for (int t = 0; t < 2; ++t) {
            bsf[t] = *(const bf16x8*)&lBs[(wn * 32 + t * 16 + l16) * LSTR + quad * 8];
            bff[t] = *(const bf16x8*)&lBf[(wn * 32 + t * 16 + l16) * LSTR + quad * 8];
        }
        #pragma unroll
        for (int tm = 0; tm < 4; ++tm)
            #pragma unroll
            for (int tn = 0; tn < 2; ++tn) {
                accS[tm][tn] = __builtin_amdgcn_mfma_f32_16x16x32_bf16(af[tm], bsf[tn], accS[tm][tn], 0, 0, 0);
                accF[tm][tn] = __builtin_amdgcn_mfma_f32_16x16x32_bf16(af[tm], bff[tn], accF[tm][tn], 0, 0, 0);
            }
        __syncthreads();
    }
    #pragma unroll
    for (int tm = 0; tm < 4; ++tm) {
        int r0 = m0 + wm * 64 + tm * 16 + quad * 4;
        #pragma unroll
        for (int tn = 0; tn < 2; ++tn) {
            int c = n0 + wn * 32 + tn * 16 + l16;
            #pragma unroll
            for (int r = 0; r < 4; ++r) {
                slow_out[(size_t)(r0 + r) * DOUT + c] = accS[tm][tn][r];
                fast_out[(size_t)(r0 + r) * DOUT + c] = accF[tm][tn][r];
            }
        }
    }
}

// ---------------- column sum of squares of fast ----------------
__global__ __launch_bounds__(256) void colsumsq_kernel(const float* __restrict__ fast,
                                                       float* __restrict__ sums) {
    int n = blockIdx.x * 256 + threadIdx.x;
    int b0 = blockIdx.y * 1024;
    float s = 0.f;
    for (int b = 0; b < 1024; ++b) {
        float v = fast[(size_t)(b0 + b) * DOUT + n];
        s += v * v;
    }
    atomicAdd(&sums[n], s);
}

// ---------------- hebb GEMM: hebb = fast^T @ x, split-K=4 into partials ----------------
// tile 128x128, BK=32 over batch; LDS-transpose staging (both operands batch-major)
__global__ __launch_bounds__(256) void hebb_gemm(
    const float* __restrict__ fast,   // [B, DOUT] fp32
    const short* __restrict__ Xb,     // [B, DIN] bf16
    float* __restrict__ hebb_part)    // [4][DOUT, DIN]
{
    __shared__ short lA[128 * LSTR];  // lA[m][b]
    __shared__ short lB[128 * LSTR];  // lB[n][b]
    const int tid = threadIdx.x;
    const int lane = tid & 63;
    const int wave = tid >> 6;
    const int wm = wave & 1, wn = wave >> 1;
    const int quad = lane >> 4, l16 = lane & 15;
    const int m0 = blockIdx.x * 128;
    const int n0 = blockIdx.y * 128;
    const int b0 = blockIdx.z * (B_SZ / 4);
    const int bend = b0 + (B_SZ / 4);

    f32x4 acc[4][4] = {};

    const int sb = tid >> 4;         // 0..15
    const int sc = (tid & 15) * 8;   // 0..120

    for (int bk = b0; bk < bend; bk += 32) {
        #pragma unroll
        for (int p = 0; p < 2; ++p) {
            int b = p * 16 + sb;
            const float4 f0 = *(const float4*)&fast[(size_t)(bk + b) * DOUT + m0 + sc];
            const float4 f1 = *(const float4*)&fast[(size_t)(bk + b) * DOUT + m0 + sc + 4];
            lA[(sc + 0) * LSTR + b] = f2bf(f0.x);
            lA[(sc + 1) * LSTR + b] = f2bf(f0.y);
            lA[(sc + 2) * LSTR + b] = f2bf(f0.z);
            lA[(sc + 3) * LSTR + b] = f2bf(f0.w);
            lA[(sc + 4) * LSTR + b] = f2bf(f1.x);
            lA[(sc + 5) * LSTR + b] = f2bf(f1.y);
            lA[(sc + 6) * LSTR + b] = f2bf(f1.z);
            lA[(sc + 7) * LSTR + b] = f2bf(f1.w);
            bf16x8 xv = *(const bf16x8*)&Xb[(size_t)(bk + b) * DIN + n0 + sc];
            #pragma unroll
            for (int i = 0; i < 8; ++i) lB[(sc + i) * LSTR + b] = xv[i];
        }
        __syncthreads();
        bf16x8 af[4], bf_[4];
        #pragma unroll
        for (int t = 0; t < 4; ++t) {
            af[t]  = *(const bf16x8*)&lA[(wm * 64 + t * 16 + l16) * LSTR + quad * 8];
            bf_[t] = *(const bf16x8*)&lB[(wn * 64 + t * 16 + l16) * LSTR + quad * 8];
        }
        #pragma unroll
        for (int tm = 0; tm < 4; ++tm)
            #pragma unroll
            for (int tn = 0; tn < 4; ++tn)
                acc[tm][tn] = __builtin_amdgcn_mfma_f32_16x16x32_bf16(af[tm], bf_[tn], acc[tm][tn], 0, 0, 0);
        __syncthreads();
    }
    float* dst = hebb_part + (size_t)blockIdx.z * DOUT * DIN;
    #pragma unroll
    for (int tm = 0; tm < 4; ++tm) {
        int r0 = m0 + wm * 64 + tm * 16 + quad * 4;
        #pragma unroll
        for (int tn = 0; tn < 4; ++tn) {
            int c = n0 + wn * 64 + tn * 16 + l16;
            #pragma unroll
            for (int r = 0; r < 4; ++r)
                dst[(size_t)(r0 + r) * DIN + c] = acc[tm][tn][r];
        }
    }
}

// ---------------- W_fast update with tanh epilogue ----------------
__global__ __launch_bounds__(256) void wfast_update(
    const float* __restrict__ Wf, const float* __restrict__ hebb_part,
    const float* __restrict__ colsumsq, const float* __restrict__ eff_lr,
    float* __restrict__ Wf_new)
{
    int i = blockIdx.x * 256 + threadIdx.x;
    int m = i >> 10;
    float lr = eff_lr[0];
    float w = Wf[i];
    const size_t sz = (size_t)DOUT * DIN;
    float h = hebb_part[i] + hebb_part[i + sz] + hebb_part[i + 2 * sz] + hebb_part[i + 3 * sz];
    float hb = h * (1.0f / (float)B_SZ);
    float fg = colsumsq[m] * (1.0f / (float)B_SZ) * w;
    Wf_new[i] = w + tanhf(hb - fg) * lr;
}

// ---------------- combine + LayerNorm (in-place over fast) ----------------
__global__ __launch_bounds__(256) void ln_kernel(
    const float* __restrict__ slow, float* __restrict__ io,   // io holds fast, becomes out
    const float* __restrict__ gamma, const float* __restrict__ beta,
    const float* __restrict__ alpha)
{
    const int row = blockIdx.x;
    const int tid = threadIdx.x;
    const float a = alpha[0];
    const size_t base = (size_t)row * DOUT;
    float c[4];
    float s = 0.f, ss = 0.f;
    #pragma unroll
    for (int i = 0; i < 4; ++i) {
        int col = tid + i * 256;
        float v = slow[base + col] + a * io[base + col];
        c[i] = v; s += v; ss += v * v;
    }
    #pragma unroll
    for (int off = 32; off > 0; off >>= 1) {
        s  += __shfl_down(s, off);
        ss += __shfl_down(ss, off);
    }
    __shared__ float rs[4], rss[4];
    int wave = tid >> 6;
    if ((tid & 63) == 0) { rs[wave] = s; rss[wave] = ss; }
    __syncthreads();
    float S  = rs[0] + rs[1] + rs[2] + rs[3];
    float SS = rss[0] + rss[1] + rss[2] + rss[3];
    float mu = S * (1.0f / DOUT);
    float var = SS * (1.0f / DOUT) - mu * mu;
    float inv = rsqrtf(var + 1e-5f);
    #pragma unroll
    for (int i = 0; i < 4; ++i) {
        int col = tid + i * 256;
        io[base + col] = (c[i] - mu) * inv * gamma[col] + beta[col];
    }
}

extern "C" void kernel_launch(void* const* d_in, const int* in_sizes, int n_in,
                              void* d_out, int out_size, void* d_ws, size_t ws_size,
                              hipStream_t stream)
{
    const float* x     = (const float*)d_in[0];
    const float* plast = (const float*)d_in[1];
    const float* alpha = (const float*)d_in[2];
    const float* Wslow = (const float*)d_in[3];
    const float* Wfast = (const float*)d_in[4];
    const float* gamma = (const float*)d_in[5];
    const float* beta  = (const float*)d_in[6];

    float* out   = (float*)d_out;                         // [B, DOUT]; holds fast until LN
    float* slow  = out + (size_t)B_SZ * DOUT;             // [B, DOUT]
    float* wfnew = slow + (size_t)B_SZ * DOUT;            // [DOUT, DIN]

    char* ws = (char*)d_ws;
    short* xb   = (short*)ws;                                   // 32 MB
    short* wsb  = (short*)(ws + (size_t)B_SZ * DIN * 2);        // 2 MB
    short* wfb  = wsb + (size_t)DOUT * DIN;                     // 2 MB
    float* hebb = (float*)(wfb + (size_t)DOUT * DIN);           // 4 x 4 MB partials
    float* csq  = hebb + (size_t)4 * DOUT * DIN;                // 4 KB
    float* efflr = csq + DOUT;                                  // 4 B

    convert_f32_bf16<<<(B_SZ * DIN / 4 + 255) / 256, 256, 0, stream>>>(x, xb, B_SZ * DIN / 4);
    convert_f32_bf16<<<(DOUT * DIN / 4 + 255) / 256, 256, 0, stream>>>(Wslow, wsb, DOUT * DIN / 4);
    convert_f32_bf16<<<(DOUT * DIN / 4 + 255) / 256, 256, 0, stream>>>(Wfast, wfb, DOUT * DIN / 4);
    init_kernel<<<1, 256, 0, stream>>>(plast, efflr, csq);
    dual_gemm<<<dim3(B_SZ / 128, DOUT / 64), 256, 0, stream>>>(xb, wsb, wfb, slow, out);
    colsumsq_kernel<<<dim3(4, 16), 256, 0, stream>>>(out, csq);
    hebb_gemm<<<dim3(8, 8, 4), 256, 0, stream>>>(out, xb, hebb);
    wfast_update<<<(DOUT * DIN) / 256, 256, 0, stream>>>(Wfast, hebb, csq, efflr, wfnew);
    ln_kernel<<<B_SZ, 256, 0, stream>>>(slow, out, gamma, beta, alpha);
}

// Round 2
// 437.263 us; speedup vs baseline: 1.6226x; 1.6226x over previous
//
#include <hip/hip_runtime.h>
#include <cstdint>
#include <cstddef>

#define B_SZ 16384
#define DIN  1024
#define DOUT 1024
#define SPLITK 8

typedef short bf16x8 __attribute__((ext_vector_type(8)));
typedef float f32x4  __attribute__((ext_vector_type(4)));

static __device__ __forceinline__ short f2bf(float f) {
    union { float f; unsigned u; } v; v.f = f;
    unsigned r = v.u + 0x7fffu + ((v.u >> 16) & 1u);
    return (short)(r >> 16);
}
static __device__ __forceinline__ float bf2f(short s) {
    union { unsigned u; float f; } v; v.u = ((unsigned)(unsigned short)s) << 16;
    return v.f;
}
// async global->LDS, 16B per lane; LDS dest is wave-uniform base + lane*16
static __device__ __forceinline__ void gload_lds16(const short* g, short* l) {
    __builtin_amdgcn_global_load_lds(
        (const __attribute__((address_space(1))) void*)g,
        (__attribute__((address_space(3))) void*)l, 16, 0, 0);
}

// ---------------- fp32 -> bf16 convert (for weights) ----------------
__global__ __launch_bounds__(256) void convert_f32_bf16(const float* __restrict__ in,
                                                        short* __restrict__ out, int n4) {
    int i = blockIdx.x * 256 + threadIdx.x;
    if (i < n4) {
        float4 v = ((const float4*)in)[i];
        short4 o;
        o.x = f2bf(v.x); o.y = f2bf(v.y); o.z = f2bf(v.z); o.w = f2bf(v.w);
        ((short4*)out)[i] = o;
    }
}

// ---------------- x: fp32 [B,DIN] -> xb bf16 [B,DIN] + xT bf16 [DIN,B] ----------------
__global__ __launch_bounds__(256) void x_convert(const float* __restrict__ x,
                                                 short* __restrict__ xb,
                                                 short* __restrict__ xT) {
    __shared__ short t[64 * 72];
    const int b0 = blockIdx.x * 64;
    const int d0 = blockIdx.y * 64;
    const int tid = threadIdx.x;
    const int r = tid >> 2;            // batch row 0..63
    const int c = (tid & 3) * 16;      // col seg
    short loc[16];
    #pragma unroll
    for (int i = 0; i < 4; ++i) {
        float4 v = *(const float4*)&x[(size_t)(b0 + r) * DIN + d0 + c + i * 4];
        loc[i * 4 + 0] = f2bf(v.x); loc[i * 4 + 1] = f2bf(v.y);
        loc[i * 4 + 2] = f2bf(v.z); loc[i * 4 + 3] = f2bf(v.w);
    }
    *(bf16x8*)&xb[(size_t)(b0 + r) * DIN + d0 + c]     = *(bf16x8*)&loc[0];
    *(bf16x8*)&xb[(size_t)(b0 + r) * DIN + d0 + c + 8] = *(bf16x8*)&loc[8];
    #pragma unroll
    for (int i = 0; i < 16; ++i) t[(c + i) * 72 + r] = loc[i];
    __syncthreads();
    const int d = tid >> 2, bs = (tid & 3) * 16;
    *(bf16x8*)&xT[(size_t)(d0 + d) * B_SZ + b0 + bs]     = *(bf16x8*)&t[d * 72 + bs];
    *(bf16x8*)&xT[(size_t)(d0 + d) * B_SZ + b0 + bs + 8] = *(bf16x8*)&t[d * 72 + bs + 8];
}

// ---------------- fast fp32 [B,DOUT] -> fastT bf16 [DOUT,B] ----------------
__global__ __launch_bounds__(256) void fast_trans(const float* __restrict__ fast,
                                                  short* __restrict__ fastT) {
    __shared__ short t[64 * 72];
    const int b0 = blockIdx.x * 64;
    const int d0 = blockIdx.y * 64;
    const int tid = threadIdx.x;
    const int r = tid >> 2;
    const int c = (tid & 3) * 16;
    short loc[16];
    #pragma unroll
    for (int i = 0; i < 4; ++i) {
        float4 v = *(const float4*)&fast[(size_t)(b0 + r) * DOUT + d0 + c + i * 4];
        loc[i * 4 + 0] = f2bf(v.x); loc[i * 4 + 1] = f2bf(v.y);
        loc[i * 4 + 2] = f2bf(v.z); loc[i * 4 + 3] = f2bf(v.w);
    }
    #pragma unroll
    for (int i = 0; i < 16; ++i) t[(c + i) * 72 + r] = loc[i];
    __syncthreads();
    const int d = tid >> 2, bs = (tid & 3) * 16;
    *(bf16x8*)&fastT[(size_t)(d0 + d) * B_SZ + b0 + bs]     = *(bf16x8*)&t[d * 72 + bs];
    *(bf16x8*)&fastT[(size_t)(d0 + d) * B_SZ + b0 + bs + 8] = *(bf16x8*)&t[d * 72 + bs + 8];
}

// ---------------- init: eff_lr ----------------
__global__ __launch_bounds__(256) void init_kernel(const float* __restrict__ plast,
                                                   float* __restrict__ eff_lr) {
    int tid = threadIdx.x;
    float s = 0.f;
    for (int i = tid; i < B_SZ; i += 256) s += plast[i];
    __shared__ float red[256];
    red[tid] = s; __syncthreads();
    for (int off = 128; off > 0; off >>= 1) {
        if (tid < off) red[tid] += red[tid + off];
        __syncthreads();
    }
    if (tid == 0) eff_lr[0] = (red[0] / (float)B_SZ) * 0.1f;
}

// ---------------- dual GEMM (m97 structure): C[B,2048] = xb @ wcat^T ----------------
// 128x128 tile, BK=32, global_load_lds staging, 4 waves as 2x2
__global__ __launch_bounds__(256) void dual_gemm(
    const short* __restrict__ Xb,    // [B, DIN]
    const short* __restrict__ Wc,    // [2048, DIN] (Ws rows 0..1023, Wf rows 1024..2047)
    float* __restrict__ slow_out,    // [B, 1024]
    float* __restrict__ fast_out)    // [B, 1024]
{
    __shared__ short lA[128 * 32];
    __shared__ short lB[128 * 32];
    const int tid = threadIdx.x;
    const int lane = tid & 63;
    const int wave = tid >> 6;
    const int wm = wave & 1, wn = wave >> 1;
    const int quad = lane >> 4, l16 = lane & 15;
    const int m0 = blockIdx.x * 128;
    const int n0 = blockIdx.y * 128;
    const int lrow = lane >> 2;        // 0..15
    const int lcol = (lane & 3) * 8;   // shorts

    f32x4 acc[4][4] = {};

    const short* gA0 = &Xb[(size_t)(m0 + wave * 32 + lrow) * DIN + lcol];
    const short* gA1 = gA0 + (size_t)16 * DIN;
    const short* gB0 = &Wc[(size_t)(n0 + wave * 32 + lrow) * DIN + lcol];
    const short* gB1 = gB0 + (size_t)16 * DIN;
    short* sA0 = &lA[(wave * 32) * 32];
    short* sA1 = &lA[(wave * 32 + 16) * 32];
    short* sB0 = &lB[(wave * 32) * 32];
    short* sB1 = &lB[(wave * 32 + 16) * 32];

    for (int k0 = 0; k0 < DIN; k0 += 32) {
        gload_lds16(gA0 + k0, sA0);
        gload_lds16(gA1 + k0, sA1);
        gload_lds16(gB0 + k0, sB0);
        gload_lds16(gB1 + k0, sB1);
        __syncthreads();
        bf16x8 af[4], bfr[4];
        #pragma unroll
        for (int t = 0; t < 4; ++t) {
            af[t]  = *(const bf16x8*)&lA[(wm * 64 + t * 16 + l16) * 32 + quad * 8];
            bfr[t] = *(const bf16x8*)&lB[(wn * 64 + t * 16 + l16) * 32 + quad * 8];
        }
        #pragma unroll
        for (int tm = 0; tm < 4; ++tm)
            #pragma unroll
            for (int tn = 0; tn < 4; ++tn)
                acc[tm][tn] = __builtin_amdgcn_mfma_f32_16x16x32_bf16(af[tm], bfr[tn], acc[tm][tn], 0, 0, 0);
        __syncthreads();
    }
    float* dst = (n0 < 1024) ? slow_out : fast_out;
    const int cb = (n0 < 1024) ? n0 : n0 - 1024;
    #pragma unroll
    for (int tm = 0; tm < 4; ++tm) {
        int r0 = m0 + wm * 64 + tm * 16 + quad * 4;
        #pragma unroll
        for (int tn = 0; tn < 4; ++tn) {
            int cc = cb + wn * 64 + tn * 16 + l16;
            #pragma unroll
            for (int r = 0; r < 4; ++r)
                dst[(size_t)(r0 + r) * 1024 + cc] = acc[tm][tn][r];
        }
    }
}

// ---------------- hebb GEMM (m97 structure, split-K): hebb = fastT @ xT^T ----------------
__global__ __launch_bounds__(256) void hebb_gemm(
    const short* __restrict__ fastT,  // [DOUT, B]
    const short* __restrict__ xT,     // [DIN, B]
    short* __restrict__ hebb_part)    // [SPLITK][DOUT, DIN] bf16
{
    __shared__ short lA[128 * 32];
    __shared__ short lB[128 * 32];
    const int tid = threadIdx.x;
    const int lane = tid & 63;
    const int wave = tid >> 6;
    const int wm = wave & 1, wn = wave >> 1;
    const int quad = lane >> 4, l16 = lane & 15;
    const int m0 = blockIdx.x * 128;   // dout
    const int n0 = blockIdx.y * 128;   // din
    const int kb = blockIdx.z * (B_SZ / SPLITK);
    const int lrow = lane >> 2;
    const int lcol = (lane & 3) * 8;

    f32x4 acc[4][4] = {};

    const short* gA0 = &fastT[(size_t)(m0 + wave * 32 + lrow) * B_SZ + kb + lcol];
    const short* gA1 = gA0 + (size_t)16 * B_SZ;
    const short* gB0 = &xT[(size_t)(n0 + wave * 32 + lrow) * B_SZ + kb + lcol];
    const short* gB1 = gB0 + (size_t)16 * B_SZ;
    short* sA0 = &lA[(wave * 32) * 32];
    short* sA1 = &lA[(wave * 32 + 16) * 32];
    short* sB0 = &lB[(wave * 32) * 32];
    short* sB1 = &lB[(wave * 32 + 16) * 32];

    for (int k0 = 0; k0 < B_SZ / SPLITK; k0 += 32) {
        gload_lds16(gA0 + k0, sA0);
        gload_lds16(gA1 + k0, sA1);
        gload_lds16(gB0 + k0, sB0);
        gload_lds16(gB1 + k0, sB1);
        __syncthreads();
        bf16x8 af[4], bfr[4];
        #pragma unroll
        for (int t = 0; t < 4; ++t) {
            af[t]  = *(const bf16x8*)&lA[(wm * 64 + t * 16 + l16) * 32 + quad * 8];
            bfr[t] = *(const bf16x8*)&lB[(wn * 64 + t * 16 + l16) * 32 + quad * 8];
        }
        #pragma unroll
        for (int tm = 0; tm < 4; ++tm)
            #pragma unroll
            for (int tn = 0; tn < 4; ++tn)
                acc[tm][tn] = __builtin_amdgcn_mfma_f32_16x16x32_bf16(af[tm], bfr[tn], acc[tm][tn], 0, 0, 0);
        __syncthreads();
    }
    short* dst = hebb_part + (size_t)blockIdx.z * DOUT * DIN;
    #pragma unroll
    for (int tm = 0; tm < 4; ++tm) {
        int r0 = m0 + wm * 64 + tm * 16 + quad * 4;
        #pragma unroll
        for (int tn = 0; tn < 4; ++tn) {
            int cc = n0 + wn * 64 + tn * 16 + l16;
            #pragma unroll
            for (int r = 0; r < 4; ++r)
                dst[(size_t)(r0 + r) * DIN + cc] = f2bf(acc[tm][tn][r]);
        }
    }
}

// ---------------- colsumsq from fastT (deterministic, no atomics) ----------------
__global__ __launch_bounds__(256) void colsumsq_kernel(const short* __restrict__ fastT,
                                                       float* __restrict__ sums) {
    const int m = blockIdx.x;
    const int tid = threadIdx.x;
    const short* row = &fastT[(size_t)m * B_SZ];
    float s = 0.f;
    for (int i = tid * 8; i < B_SZ; i += 256 * 8) {
        bf16x8 v = *(const bf16x8*)&row[i];
        #pragma unroll
        for (int j = 0; j < 8; ++j) { float f = bf2f(v[j]); s += f * f; }
    }
    __shared__ float red[256];
    red[tid] = s; __syncthreads();
    for (int off = 128; off > 0; off >>= 1) {
        if (tid < off) red[tid] += red[tid + off];
        __syncthreads();
    }
    if (tid == 0) sums[m] = red[0];
}

// ---------------- W_fast update with tanh epilogue ----------------
__global__ __launch_bounds__(256) void wfast_update(
    const float* __restrict__ Wf, const short* __restrict__ hebb_part,
    const float* __restrict__ colsumsq, const float* __restrict__ eff_lr,
    float* __restrict__ Wf_new)
{
    const int i0 = (blockIdx.x * 256 + threadIdx.x) * 8;
    const int m = i0 >> 10;
    const float lr = eff_lr[0];
    const float fgm = colsumsq[m] * (1.0f / (float)B_SZ);
    float h[8] = {0.f, 0.f, 0.f, 0.f, 0.f, 0.f, 0.f, 0.f};
    #pragma unroll
    for (int z = 0; z < SPLITK; ++z) {
        bf16x8 v = *(const bf16x8*)&hebb_part[(size_t)z * DOUT * DIN + i0];
        #pragma unroll
        for (int j = 0; j < 8; ++j) h[j] += bf2f(v[j]);
    }
    float4 w0 = *(const float4*)&Wf[i0];
    float4 w1 = *(const float4*)&Wf[i0 + 4];
    float w[8] = {w0.x, w0.y, w0.z, w0.w, w1.x, w1.y, w1.z, w1.w};
    float o[8];
    #pragma unroll
    for (int j = 0; j < 8; ++j)
        o[j] = w[j] + tanhf(h[j] * (1.0f / (float)B_SZ) - fgm * w[j]) * lr;
    *(float4*)&Wf_new[i0]     = make_float4(o[0], o[1], o[2], o[3]);
    *(float4*)&Wf_new[i0 + 4] = make_float4(o[4], o[5], o[6], o[7]);
}

// ---------------- combine + LayerNorm (in-place over fast) ----------------
__global__ __launch_bounds__(256) void ln_kernel(
    const float* __restrict__ slow, float* __restrict__ io,
    const float* __restrict__ gamma, const float* __restrict__ beta,
    const float* __restrict__ alpha)
{
    const int row = blockIdx.x;
    const int tid = threadIdx.x;
    const float a = alpha[0];
    const size_t base = (size_t)row * DOUT;
    float c[4];
    float s = 0.f, ss = 0.f;
    #pragma unroll
    for (int i = 0; i < 4; ++i) {
        int col = tid + i * 256;
        float v = slow[base + col] + a * io[base + col];
        c[i] = v; s += v; ss += v * v;
    }
    #pragma unroll
    for (int off = 32; off > 0; off >>= 1) {
        s  += __shfl_down(s, off);
        ss += __shfl_down(ss, off);
    }
    __shared__ float rs[4], rss[4];
    int wave = tid >> 6;
    if ((tid & 63) == 0) { rs[wave] = s; rss[wave] = ss; }
    __syncthreads();
    float S  = rs[0] + rs[1] + rs[2] + rs[3];
    float SS = rss[0] + rss[1] + rss[2] + rss[3];
    float mu = S * (1.0f / DOUT);
    float var = SS * (1.0f / DOUT) - mu * mu;
    float inv = rsqrtf(var + 1e-5f);
    #pragma unroll
    for (int i = 0; i < 4; ++i) {
        int col = tid + i * 256;
        io[base + col] = (c[i] - mu) * inv * gamma[col] + beta[col];
    }
}

extern "C" void kernel_launch(void* const* d_in, const int* in_sizes, int n_in,
                              void* d_out, int out_size, void* d_ws, size_t ws_size,
                              hipStream_t stream)
{
    const float* x     = (const float*)d_in[0];
    const float* plast = (const float*)d_in[1];
    const float* alpha = (const float*)d_in[2];
    const float* Wslow = (const float*)d_in[3];
    const float* Wfast = (const float*)d_in[4];
    const float* gamma = (const float*)d_in[5];
    const float* beta  = (const float*)d_in[6];

    float* out   = (float*)d_out;                 // [B, DOUT]; holds fast until LN
    float* slow  = out + (size_t)B_SZ * DOUT;     // [B, DOUT]
    float* wfnew = slow + (size_t)B_SZ * DOUT;    // [DOUT, DIN]

    // workspace layout (region A reused: xb until dual_gemm done, then fastT)
    char* ws = (char*)d_ws;
    short* xb    = (short*)ws;                                  // 32 MB
    short* fastT = xb;                                          // alias (xb dead after dual_gemm)
    short* xT    = (short*)(ws + (size_t)B_SZ * DIN * 2);       // 32 MB
    short* wcat  = xT + (size_t)DIN * B_SZ;                     // 4 MB [2048,1024]
    short* hebb  = wcat + (size_t)2048 * DIN;                   // 16 MB bf16 partials
    float* csq   = (float*)(hebb + (size_t)SPLITK * DOUT * DIN);
    float* efflr = csq + DOUT;

    x_convert<<<dim3(B_SZ / 64, DIN / 64), 256, 0, stream>>>(x, xb, xT);
    convert_f32_bf16<<<(DOUT * DIN / 4 + 255) / 256, 256, 0, stream>>>(Wslow, wcat, DOUT * DIN / 4);
    convert_f32_bf16<<<(DOUT * DIN / 4 + 255) / 256, 256, 0, stream>>>(Wfast, wcat + (size_t)DOUT * DIN, DOUT * DIN / 4);
    init_kernel<<<1, 256, 0, stream>>>(plast, efflr);
    dual_gemm<<<dim3(B_SZ / 128, 2048 / 128), 256, 0, stream>>>(xb, wcat, slow, out);
    fast_trans<<<dim3(B_SZ / 64, DOUT / 64), 256, 0, stream>>>(out, fastT);
    colsumsq_kernel<<<DOUT, 256, 0, stream>>>(fastT, csq);
    hebb_gemm<<<dim3(DOUT / 128, DIN / 128, SPLITK), 256, 0, stream>>>(fastT, xT, hebb);
    wfast_update<<<(DOUT * DIN) / (256 * 8), 256, 0, stream>>>(Wfast, hebb, csq, efflr, wfnew);
    ln_kernel<<<B_SZ, 256, 0, stream>>>(slow, out, gamma, beta, alpha);
}